// Round 8
// baseline (4587.711 us; speedup 1.0000x reference)
//
#include <hip/hip_runtime.h>

// LSTM: B=64, T=1024, D=512, H=512. Gate order i,f,g,o.
// Phase A: xW GEMM, f16 MFMA, 128x128 tile, global_load_lds w16, XOR-swizzled LDS
//   (verified r3-r6; NT hints REVERTED per r6 null/negative result).
// Phase B: persistent scan, 128 WGs = 8 row-groups(8 rows) x 16 slices(32 units).
//   Cohort g = {w : w&7==g} -> all 16 WGs of a cohort share w mod 8 -> one XCD
//   under round-robin dispatch (no handshake; self-validating).
//   Publish: agent store (proven IC path, r5) + sc0 write-through store (L2).
//   Poll: sc0 loads first (same-XCD L2, guard 512, STICKY per-thread degrade),
//   then proven agent loads (guard 4096). r1's sc0 failure was a WORKGROUP-scope
//   (plain/L1) publish -- sc0 polls read L2, data was never there. Fixed here.
//   Worst case if placement assumption wrong: one-time ~75us burn, r5 parity.
// (r7 bench = container infra failure, 3rd this session; resubmitted per r2->r3
//  precedent with agent guard halved 8192->4096 as extra bounding.)

#define B_  64
#define T_  1024
#define D_  512
#define H_  512
#define G4H 2048

typedef _Float16 half8 __attribute__((ext_vector_type(8)));
typedef _Float16 half4 __attribute__((ext_vector_type(4)));
typedef float    f32x4 __attribute__((ext_vector_type(4)));
typedef unsigned long long ull;
typedef unsigned int u32;

static __device__ __forceinline__ float sigm(float x) { return 1.f / (1.f + __expf(-x)); }
static __device__ __forceinline__ float tanh_(float x) {
    float xc = fminf(fmaxf(x, -15.f), 15.f);
    float e  = __expf(2.f * xc);
    return (e - 1.f) / (e + 1.f);
}
static __device__ __forceinline__ void gload_lds16(const _Float16* g, _Float16* l) {
    __builtin_amdgcn_global_load_lds((const __attribute__((address_space(1))) u32*)g,
                                     (__attribute__((address_space(3))) u32*)l, 16, 0, 0);
}

// ---------------- init: transpose-convert [512][2048] f32 -> [2048][512] f16
__global__ void trans_w(const float* __restrict__ W, _Float16* __restrict__ WT) {
    int idx = blockIdx.x * blockDim.x + threadIdx.x;
    int total = D_ * G4H;
    int stride = gridDim.x * blockDim.x;
    for (int i = idx; i < total; i += stride) {
        int k = i >> 11;
        int n = i & (G4H - 1);
        WT[(size_t)n * D_ + k] = (_Float16)W[i];
    }
}

// ---------------- init: x f32 -> f16
__global__ void conv_x(const float* __restrict__ x, _Float16* __restrict__ xh) {
    int idx = blockIdx.x * blockDim.x + threadIdx.x;
    int total = (B_ * T_ * D_) / 4;
    int stride = gridDim.x * blockDim.x;
    const f32x4* xi = (const f32x4*)x;
    half4* xo = (half4*)xh;
    for (int i = idx; i < total; i += stride) {
        f32x4 v = xi[i];
        xo[i] = (half4){(_Float16)v.x, (_Float16)v.y, (_Float16)v.z, (_Float16)v.w};
    }
}

__global__ void zero_buf(unsigned* __restrict__ p, int n) {
    int idx = blockIdx.x * blockDim.x + threadIdx.x;
    int stride = gridDim.x * blockDim.x;
    for (int i = idx; i < n; i += stride) p[i] = 0u;
}

// ---------------- phase A (fast): 128x128 tile, f16 A via precomputed xh (verified)
__global__ __launch_bounds__(256) void gemm_xw_f16(const _Float16* __restrict__ xh,
                                                   const _Float16* __restrict__ WkT,
                                                   const float* __restrict__ bias,
                                                   _Float16* __restrict__ xw, int tbase) {
    __shared__ _Float16 As[128 * 64];   // [row][64 k] f16, XOR-swizzled (byte ^= (row&7)<<4)
    __shared__ _Float16 Bs[128 * 64];
    const int tid  = threadIdx.x;
    const int lane = tid & 63;
    const int wave = tid >> 6;
    const int l15  = lane & 15;
    const int quad = lane >> 4;
    const int b     = blockIdx.z;
    const int n0    = blockIdx.x * 128;
    const int tloc0 = blockIdx.y * 128;

    const int srow = tid >> 3;
    const int sseg = tid & 7;

    f32x4 acc[2][8];
#pragma unroll
    for (int rt = 0; rt < 2; ++rt)
#pragma unroll
        for (int ct = 0; ct < 8; ++ct) acc[rt][ct] = (f32x4){0.f, 0.f, 0.f, 0.f};

    const _Float16* abase = xh + ((size_t)b * T_ + tbase + tloc0) * D_;
    const _Float16* bbase = WkT + (size_t)n0 * D_;

    for (int kb = 0; kb < 8; ++kb) {
        __syncthreads();
#pragma unroll
        for (int q = 0; q < 4; ++q) {
            int row  = q * 32 + srow;
            int col2 = (sseg * 16) ^ ((row & 7) << 4);
            _Float16* ldst = (_Float16*)((char*)As + q * 4096 + wave * 1024);
            gload_lds16(abase + (size_t)row * D_ + kb * 64 + (col2 >> 1), ldst);
            _Float16* ldstb = (_Float16*)((char*)Bs + q * 4096 + wave * 1024);
            gload_lds16(bbase + (size_t)row * D_ + kb * 64 + (col2 >> 1), ldstb);
        }
        __syncthreads();
#pragma unroll
        for (int ks = 0; ks < 2; ++ks) {
            half8 af[2];
#pragma unroll
            for (int rt = 0; rt < 2; ++rt) {
                int row = wave * 32 + rt * 16 + l15;
                int c2  = (ks * 64 + quad * 16) ^ ((row & 7) << 4);
                af[rt] = *(const half8*)&As[row * 64 + (c2 >> 1)];
            }
#pragma unroll
            for (int ct = 0; ct < 8; ++ct) {
                int brw = ct * 16 + l15;
                int c2  = (ks * 64 + quad * 16) ^ ((brw & 7) << 4);
                half8 bf = *(const half8*)&Bs[brw * 64 + (c2 >> 1)];
                acc[0][ct] = __builtin_amdgcn_mfma_f32_16x16x32_f16(af[0], bf, acc[0][ct], 0, 0, 0);
                acc[1][ct] = __builtin_amdgcn_mfma_f32_16x16x32_f16(af[1], bf, acc[1][ct], 0, 0, 0);
            }
        }
    }
#pragma unroll
    for (int ct = 0; ct < 8; ++ct) {
        int col = n0 + ct * 16 + l15;
        float bs = bias[col];
#pragma unroll
        for (int rt = 0; rt < 2; ++rt)
#pragma unroll
            for (int r = 0; r < 4; ++r) {
                int tt = tloc0 + wave * 32 + rt * 16 + quad * 4 + r;
                xw[((size_t)tt * B_ + b) * G4H + col] = (_Float16)(acc[rt][ct][r] + bs);
            }
    }
}

// ---------------- phase A (fallback, small ws): 64x64 kernel
__global__ __launch_bounds__(256) void gemm_xw_small(const float* __restrict__ x,
                                                     const _Float16* __restrict__ WkT,
                                                     const float* __restrict__ bias,
                                                     _Float16* __restrict__ xw,
                                                     int tbase) {
    __shared__ _Float16 As[64][40];
    __shared__ _Float16 Bst[64][40];
    const int tid  = threadIdx.x;
    const int lane = tid & 63;
    const int wave = tid >> 6;
    const int l15  = lane & 15;
    const int quad = lane >> 4;
    const int b     = blockIdx.z;
    const int n0    = blockIdx.x * 64;
    const int tloc0 = blockIdx.y * 64;

    const float* xbase = x + ((size_t)b * T_ + (tbase + tloc0)) * D_;
    f32x4 acc[4];
#pragma unroll
    for (int i = 0; i < 4; ++i) acc[i] = (f32x4){0.f, 0.f, 0.f, 0.f};

    const int ai = tid >> 2, ac = tid & 3;
    const int bn = tid >> 2, bq = tid & 3;

    for (int kb = 0; kb < 16; ++kb) {
        __syncthreads();
        const float* ap = xbase + (size_t)ai * D_ + kb * 32 + ac * 8;
        f32x4 av0 = *(const f32x4*)ap;
        f32x4 av1 = *(const f32x4*)(ap + 4);
        half8 ah = { (_Float16)av0.x, (_Float16)av0.y, (_Float16)av0.z, (_Float16)av0.w,
                     (_Float16)av1.x, (_Float16)av1.y, (_Float16)av1.z, (_Float16)av1.w };
        *(half8*)&As[ai][ac * 8] = ah;
        half8 bv = *(const half8*)(WkT + (size_t)(n0 + bn) * D_ + kb * 32 + bq * 8);
        *(half8*)&Bst[bn][bq * 8] = bv;
        __syncthreads();

        half8 afrag = *(const half8*)&As[16 * wave + l15][quad * 8];
#pragma unroll
        for (int nt = 0; nt < 4; ++nt) {
            half8 bfrag = *(const half8*)&Bst[nt * 16 + l15][quad * 8];
            acc[nt] = __builtin_amdgcn_mfma_f32_16x16x32_f16(afrag, bfrag, acc[nt], 0, 0, 0);
        }
    }
#pragma unroll
    for (int nt = 0; nt < 4; ++nt)
#pragma unroll
        for (int r = 0; r < 4; ++r) {
            int tt  = tloc0 + 16 * wave + quad * 4 + r;
            int col = n0 + nt * 16 + l15;
            xw[((size_t)tt * B_ + b) * G4H + col] = (_Float16)(acc[nt][r] + bias[col]);
        }
}

// ---------------- phase B: persistent scan, XCD-local cohorts
// 128 WGs x 256 thr. WG w: group g=w&7 (rows g*8..+7), slice s=w>>3 (units s*32..+31).
// Cohort g (16 WGs, all w==g mod 8) shares one XCD under round-robin dispatch.
// Wave v = gate v, 2 col tiles of 16 (cols v*512+u0+0..31). bfrag 128 VGPR (no spill).
// hbuf: 3 slots x [64][512] tagged dwords (lo16 = h f16, hi16 = step+1).
__global__ __launch_bounds__(256, 1) void lstm_scan(const _Float16* __restrict__ xw,
                                                    const _Float16* __restrict__ WrT,
                                                    unsigned* __restrict__ hbuf,
                                                    float* __restrict__ cio,
                                                    float* __restrict__ out,
                                                    int t0, int t1) {
    const int w    = blockIdx.x;
    const int g    = w & 7;
    const int s    = w >> 3;
    const int u0   = s * 32;
    const int tid  = threadIdx.x;
    const int lane = tid & 63;
    const int wave = tid >> 6;
    const int l15  = lane & 15;
    const int quad = lane >> 4;

    // B-frags: wave v = gate v, col tiles ct=0,1. 128 VGPRs (r5-proven layout).
    half8 bfrag[2][16];
#pragma unroll
    for (int ct = 0; ct < 2; ++ct) {
        const int col = wave * H_ + u0 + ct * 16 + l15;
        const _Float16* wp = WrT + (size_t)col * D_;
#pragma unroll
        for (int kt = 0; kt < 16; ++kt)
            bfrag[ct][kt] = *(const half8*)(wp + kt * 32 + quad * 8);
    }

    const int rho  = tid >> 5;        // batch-row in group (0..7)
    const int uu   = tid & 31;        // unit within slice (one unit per thread)
    const int brow = g * 8 + rho;
    const int un   = u0 + uu;
    float c = 0.f;
    if (t0 != 0) c = cio[(size_t)brow * H_ + un];

    __shared__ _Float16 hS[16][520];      // rows 8..15 stay zero (MFMA M-pad)
    __shared__ float    zS[8][4][34];     // z exchange

    for (int i = tid; i < 8 * 520; i += 256) ((_Float16*)&hS[8][0])[i] = (_Float16)0.f;
    __syncthreads();

    const size_t slotSz = (size_t)B_ * H_;   // dwords per slot
    bool fastok = true;   // sticky: first sc0-guard trip -> permanent agent polls

    for (int t = t0; t < t1; ++t) {
        // xw prefetch: 4 scalar f16 (one per gate) for this thread's unit
        const _Float16* xwp = xw + ((size_t)(t - t0) * B_ + brow) * G4H + un;
        float xi_ = (float)xwp[0 * 512];
        float xf_ = (float)xwp[1 * 512];
        float xg_ = (float)xwp[2 * 512];
        float xo_ = (float)xwp[3 * 512];

        if (t > 0) {
            // thread polls unit-pair column tid (units 2*tid,2*tid+1), rows 0..7 of
            // group g; producers are all in cohort g (same XCD if mapping holds).
            const ull* src = (const ull*)(hbuf + (size_t)((t - 1) % 3) * slotSz)
                             + (size_t)(g * 8) * 256 + tid;
            const unsigned tgt = (unsigned)(t & 0xffff);
            const ull expect = ((ull)tgt << 16) | ((ull)tgt << 48);
            ull v0 = 0, v1 = 0, v2 = 0, v3 = 0, v4 = 0, v5 = 0, v6 = 0, v7 = 0;
            bool got = false;
            if (fastok) {
                int guard = 0;
                while (true) {
                    asm volatile(
                        "global_load_dwordx2 %0, %8, off sc0\n\t"
                        "global_load_dwordx2 %1, %9, off sc0\n\t"
                        "global_load_dwordx2 %2, %10, off sc0\n\t"
                        "global_load_dwordx2 %3, %11, off sc0\n\t"
                        "global_load_dwordx2 %4, %12, off sc0\n\t"
                        "global_load_dwordx2 %5, %13, off sc0\n\t"
                        "global_load_dwordx2 %6, %14, off sc0\n\t"
                        "global_load_dwordx2 %7, %15, off sc0\n\t"
                        "s_waitcnt vmcnt(0)"
                        : "=&v"(v0), "=&v"(v1), "=&v"(v2), "=&v"(v3),
                          "=&v"(v4), "=&v"(v5), "=&v"(v6), "=&v"(v7)
                        : "v"(src), "v"(src + 256), "v"(src + 512), "v"(src + 768),
                          "v"(src + 1024), "v"(src + 1280), "v"(src + 1536), "v"(src + 1792)
                        : "memory");
                    ull diff = ((v0 ^ expect) | (v1 ^ expect) | (v2 ^ expect) | (v3 ^ expect)
                              | (v4 ^ expect) | (v5 ^ expect) | (v6 ^ expect) | (v7 ^ expect))
                              & 0xffff0000ffff0000ull;
                    if (diff == 0) { got = true; break; }
                    if (++guard > 512) { fastok = false; break; }   // sticky degrade
                }
            }
            if (!got) {
                int guard = 0;
                while (true) {
                    v0 = __hip_atomic_load(src + 0,    __ATOMIC_RELAXED, __HIP_MEMORY_SCOPE_AGENT);
                    v1 = __hip_atomic_load(src + 256,  __ATOMIC_RELAXED, __HIP_MEMORY_SCOPE_AGENT);
                    v2 = __hip_atomic_load(src + 512,  __ATOMIC_RELAXED, __HIP_MEMORY_SCOPE_AGENT);
                    v3 = __hip_atomic_load(src + 768,  __ATOMIC_RELAXED, __HIP_MEMORY_SCOPE_AGENT);
                    v4 = __hip_atomic_load(src + 1024, __ATOMIC_RELAXED, __HIP_MEMORY_SCOPE_AGENT);
                    v5 = __hip_atomic_load(src + 1280, __ATOMIC_RELAXED, __HIP_MEMORY_SCOPE_AGENT);
                    v6 = __hip_atomic_load(src + 1536, __ATOMIC_RELAXED, __HIP_MEMORY_SCOPE_AGENT);
                    v7 = __hip_atomic_load(src + 1792, __ATOMIC_RELAXED, __HIP_MEMORY_SCOPE_AGENT);
                    ull diff = ((v0 ^ expect) | (v1 ^ expect) | (v2 ^ expect) | (v3 ^ expect)
                              | (v4 ^ expect) | (v5 ^ expect) | (v6 ^ expect) | (v7 ^ expect))
                              & 0xffff0000ffff0000ull;
                    if (diff == 0) break;
                    if (++guard > 4096) break;   // bailout: visible failure, not a hang
                }
            }
            // strip tags, pack 2 f16 -> dword, stage rows 0..7 of pair-column tid
#define STG(k_, vk_) *(unsigned*)&hS[k_][2 * tid] = \
        (unsigned)((vk_) & 0xffffu) | ((unsigned)((vk_) >> 32) << 16);
            STG(0, v0) STG(1, v1) STG(2, v2) STG(3, v3)
            STG(4, v4) STG(5, v5) STG(6, v6) STG(7, v7)
#undef STG
        }
        __syncthreads();   // BARRIER1: hS staged (also fences hS reuse per r5 analysis)

        f32x4 a0 = {0.f,0.f,0.f,0.f}, a1 = a0, b0 = a0, b1 = a0;
        if (t > 0) {
#pragma unroll
            for (int kt = 0; kt < 16; kt += 2) {
                half8 af0 = *(const half8*)&hS[l15][kt * 32 + quad * 8];
                half8 af1 = *(const half8*)&hS[l15][(kt + 1) * 32 + quad * 8];
                a0 = __builtin_amdgcn_mfma_f32_16x16x32_f16(af0, bfrag[0][kt],     a0, 0, 0, 0);
                a1 = __builtin_amdgcn_mfma_f32_16x16x32_f16(af0, bfrag[1][kt],     a1, 0, 0, 0);
                b0 = __builtin_amdgcn_mfma_f32_16x16x32_f16(af1, bfrag[0][kt + 1], b0, 0, 0, 0);
                b1 = __builtin_amdgcn_mfma_f32_16x16x32_f16(af1, bfrag[1][kt + 1], b1, 0, 0, 0);
            }
        }
        f32x4 z0 = a0 + b0, z1 = a1 + b1;
        if (quad < 2) {   // C rows 0..7 are the real batch rows
#pragma unroll
            for (int r = 0; r < 4; ++r) {
                zS[quad * 4 + r][wave][l15]      = z0[r];
                zS[quad * 4 + r][wave][16 + l15] = z1[r];
            }
        }
        __syncthreads();   // BARRIER2: zS ready

        float zi = zS[rho][0][uu] + xi_;
        float zf = zS[rho][1][uu] + xf_;
        float zg = zS[rho][2][uu] + xg_;
        float zo = zS[rho][3][uu] + xo_;

        c = sigm(zf) * c + sigm(zi) * tanh_(zg);
        float h = sigm(zo) * tanh_(c);

        // tagged publish, dual: agent store (IC, proven) THEN sc0 write-through (L2,
        // fast same-XCD consumers). Same bytes -> order irrelevant for correctness.
        unsigned d = (unsigned)__builtin_bit_cast(unsigned short, (_Float16)h)
                   | (((unsigned)((t + 1) & 0xffff)) << 16);
        unsigned* dst = hbuf + (size_t)(t % 3) * slotSz + (size_t)brow * H_ + un;
        __hip_atomic_store(dst, d, __ATOMIC_RELAXED, __HIP_MEMORY_SCOPE_AGENT);
        asm volatile("global_store_dword %0, %1, off sc0" :: "v"(dst), "v"(d) : "memory");

        if (t == T_ - 1) out[(size_t)brow * H_ + un] = h;
    }
    cio[(size_t)brow * H_ + un] = c;
}

// ---------------- launch
extern "C" void kernel_launch(void* const* d_in, const int* in_sizes, int n_in,
                              void* d_out, int out_size, void* d_ws, size_t ws_size,
                              hipStream_t stream) {
    (void)in_sizes; (void)n_in;
    const float* x    = (const float*)d_in[0];
    const float* Wk   = (const float*)d_in[1];
    const float* Wr   = (const float*)d_in[2];
    const float* bias = (const float*)d_in[3];
    float* out = (float*)d_out;

    char* ws = (char*)d_ws;
    _Float16* WkT  = (_Float16*)(ws + 1024);                      // 2 MB
    _Float16* WrT  = (_Float16*)(ws + 1024 + 2097152);            // 2 MB
    unsigned* hbuf = (unsigned*)(ws + 1024 + 2 * 2097152);        // 384 KB (3 slots)
    float*    cio  = (float*)(ws + 1024 + 2 * 2097152 + 393216);  // 128 KB
    const size_t fixed   = 1024 + 2 * 2097152 + 393216 + 131072;
    const size_t xhBytes = (size_t)B_ * T_ * D_ * 2;              // 64 MB
    const size_t perT    = (size_t)B_ * G4H * 2;                  // 256 KB per timestep

    size_t avail = (ws_size > fixed) ? ws_size - fixed : 0;
    bool use_xh = avail >= xhBytes + 128 * perT;
    _Float16* xh = (_Float16*)(ws + fixed);
    _Float16* xw = (_Float16*)(ws + fixed + (use_xh ? xhBytes : 0));

    int ct = 0;
    if (use_xh) {
        const int cands[4] = {1024, 512, 256, 128};
        size_t av2 = avail - xhBytes;
        for (int i = 0; i < 4; ++i)
            if ((size_t)cands[i] * perT <= av2) { ct = cands[i]; break; }
    } else {
        const int cands[5] = {1024, 512, 256, 128, 64};
        for (int i = 0; i < 5; ++i)
            if ((size_t)cands[i] * perT <= avail) { ct = cands[i]; break; }
    }
    if (ct == 0) {
        hipMemsetAsync(d_out, 0, (size_t)out_size * 4, stream);
        return;
    }

    zero_buf<<<96, 256, 0, stream>>>(hbuf, 3 * B_ * H_);
    trans_w<<<512, 256, 0, stream>>>(Wk, WkT);
    trans_w<<<512, 256, 0, stream>>>(Wr, WrT);
    if (use_xh) conv_x<<<2048, 256, 0, stream>>>(x, xh);

    for (int t0 = 0; t0 < T_; t0 += ct) {
        if (use_xh)
            gemm_xw_f16<<<dim3(16, ct / 128, B_), 256, 0, stream>>>(xh, WkT, bias, xw, t0);
        else
            gemm_xw_small<<<dim3(32, ct / 64, B_), 256, 0, stream>>>(x, WkT, bias, xw, t0);
        lstm_scan<<<128, 256, 0, stream>>>(xw, WrT, hbuf, cio, out, t0, t0 + ct);
    }
}